// Round 3
// baseline (1529.441 us; speedup 1.0000x reference)
//
#include <hip/hip_runtime.h>
#include <hip/hip_bf16.h>
#include <cstdint>
#include <cstddef>

#define EPS_IN 1e-5f

// ---------------------------------------------------------------------------
// Instance-norm + residual: y = (x - mean) * rsqrt(var + eps) + x
// One block (256 threads) per channel.
// ---------------------------------------------------------------------------
__global__ void inorm_res_kernel(const float* __restrict__ in, float* __restrict__ out, int HW) {
    int c = blockIdx.x;
    const float* src = in + (size_t)c * HW;
    float* dst = out + (size_t)c * HW;
    float s = 0.f, q = 0.f;
    for (int i = threadIdx.x; i < HW; i += blockDim.x) {
        float v = src[i];
        s += v; q += v * v;
    }
#pragma unroll
    for (int off = 32; off >= 1; off >>= 1) {
        s += __shfl_down(s, off, 64);
        q += __shfl_down(q, off, 64);
    }
    __shared__ float ss[4], sq[4], mr[2];
    int wave = threadIdx.x >> 6;
    if ((threadIdx.x & 63) == 0) { ss[wave] = s; sq[wave] = q; }
    __syncthreads();
    if (threadIdx.x == 0) {
        float ts = ss[0] + ss[1] + ss[2] + ss[3];
        float tq = sq[0] + sq[1] + sq[2] + sq[3];
        float m = ts / (float)HW;
        float var = tq / (float)HW - m * m;
        mr[0] = m;
        mr[1] = rsqrtf(var + EPS_IN);
    }
    __syncthreads();
    float m = mr[0], r = mr[1];
    for (int i = threadIdx.x; i < HW; i += blockDim.x) {
        float v = src[i];
        dst[i] = (v - m) * r + v;
    }
}

// ---------------------------------------------------------------------------
// Direct 3x3 SAME conv, NCHW, weights (O, Cin, 3, 3) fp32.
// Register-blocked: each thread computes 4 consecutive pixels (same row)
// x OBLK output channels. Block covers 1024 contiguous pixels (W | 1024).
// Per c-iter: 144 FMA (OBLK=4) vs 36 LDS reads + ~9 mem insts.
// ---------------------------------------------------------------------------
template <int OBLK>
__global__ void conv3x3_kernel(const float* __restrict__ in, const float* __restrict__ w,
                               const float* __restrict__ bias, float* __restrict__ out,
                               int Cin, int H, int W) {
    extern __shared__ float wsm[];   // [Cin][9][OBLK]
    int o0 = blockIdx.y * OBLK;
    int n = Cin * 9 * OBLK;
    for (int t = threadIdx.x; t < n; t += blockDim.x) {
        int ob = t % OBLK;
        int tap = (t / OBLK) % 9;
        int c = t / (9 * OBLK);
        wsm[t] = w[((size_t)(o0 + ob) * Cin + c) * 9 + tap];
    }
    __syncthreads();
    int HW = H * W;
    int tpr = W >> 2;                       // threads per row (4 px/thread)
    int rows_per_blk = blockDim.x / tpr;    // 1024 / W
    int y = blockIdx.x * rows_per_blk + (int)(threadIdx.x / tpr);
    int x0 = (threadIdx.x % tpr) * 4;

    float acc[OBLK][4];
#pragma unroll
    for (int ob = 0; ob < OBLK; ob++) {
        float b = bias[o0 + ob];
#pragma unroll
        for (int p = 0; p < 4; p++) acc[ob][p] = b;
    }
    bool xl = (x0 > 0), xr = (x0 + 4 < W);
    for (int c = 0; c < Cin; c++) {
        const float* base = in + (size_t)c * HW + (size_t)y * W + x0;
        const float* wc = wsm + (size_t)c * 9 * OBLK;
#pragma unroll
        for (int dy = 0; dy < 3; dy++) {
            int yy = y + dy - 1;
            if (yy < 0 || yy >= H) continue;
            const float* row = base + (dy - 1) * W;
            float v[6];
            v[0] = xl ? row[-1] : 0.f;
            float4 m = *(const float4*)row;     // x0 % 4 == 0 -> 16B aligned
            v[1] = m.x; v[2] = m.y; v[3] = m.z; v[4] = m.w;
            v[5] = xr ? row[4] : 0.f;
#pragma unroll
            for (int dx = 0; dx < 3; dx++) {
                const float* wt = wc + (dy * 3 + dx) * OBLK;
#pragma unroll
                for (int ob = 0; ob < OBLK; ob++) {
                    float wv = wt[ob];
#pragma unroll
                    for (int p = 0; p < 4; p++)
                        acc[ob][p] += v[dx + p] * wv;
                }
            }
        }
    }
#pragma unroll
    for (int ob = 0; ob < OBLK; ob++) {
        float4 st;
        st.x = acc[ob][0]; st.y = acc[ob][1]; st.z = acc[ob][2]; st.w = acc[ob][3];
        *(float4*)(out + (size_t)(o0 + ob) * HW + (size_t)y * W + x0) = st;
    }
}

// ---------------------------------------------------------------------------
// PAC adaptive kernel weights, single pass over the guide computing all 9
// taps: kk[tap][y][x] = exp(-0.5 * sum_c (gp_shift - g)^2), gp zero-padded.
// PIX consecutive pixels per thread; 64-thread blocks for block-count.
// ---------------------------------------------------------------------------
template <int PIX>
__global__ void kk_kernel(const float* __restrict__ g, float* __restrict__ kkout,
                          int Cg, int H, int W) {
    int tpr = W / PIX;
    int idx = blockIdx.x * blockDim.x + threadIdx.x;
    int y = idx / tpr;
    int x0 = (idx % tpr) * PIX;
    int HW = H * W;
    float s[9][PIX];
#pragma unroll
    for (int t = 0; t < 9; t++)
#pragma unroll
        for (int p = 0; p < PIX; p++) s[t][p] = 0.f;

    bool xl = (x0 > 0), xr = (x0 + PIX < W);
    for (int c = 0; c < Cg; c++) {
        const float* gc = g + (size_t)c * HW + (size_t)y * W + x0;
        float ctr[PIX];
        if constexpr (PIX == 4) {
            float4 m = *(const float4*)gc;
            ctr[0] = m.x; ctr[1] = m.y; ctr[2] = m.z; ctr[3] = m.w;
        } else {
            float2 m = *(const float2*)gc;
            ctr[0] = m.x; ctr[1] = m.y;
        }
        float rv[3][PIX + 2];
#pragma unroll
        for (int dy = 0; dy < 3; dy++) {
            int yy = y + dy - 1;
            if (yy < 0 || yy >= H) {
#pragma unroll
                for (int t = 0; t < PIX + 2; t++) rv[dy][t] = 0.f;
            } else {
                const float* row = gc + (size_t)(dy - 1) * W;
                rv[dy][0] = xl ? row[-1] : 0.f;
                if constexpr (PIX == 4) {
                    float4 m = *(const float4*)row;
                    rv[dy][1] = m.x; rv[dy][2] = m.y; rv[dy][3] = m.z; rv[dy][4] = m.w;
                } else {
                    float2 m = *(const float2*)row;
                    rv[dy][1] = m.x; rv[dy][2] = m.y;
                }
                rv[dy][PIX + 1] = xr ? row[PIX] : 0.f;
            }
        }
#pragma unroll
        for (int dy = 0; dy < 3; dy++)
#pragma unroll
            for (int dx = 0; dx < 3; dx++)
#pragma unroll
                for (int p = 0; p < PIX; p++) {
                    float d = rv[dy][dx + p] - ctr[p];
                    s[dy * 3 + dx][p] += d * d;
                }
    }
#pragma unroll
    for (int t = 0; t < 9; t++) {
        float* o = kkout + (size_t)t * HW + (size_t)y * W + x0;
        if constexpr (PIX == 4) {
            float4 st;
            st.x = __expf(-0.5f * s[t][0]); st.y = __expf(-0.5f * s[t][1]);
            st.z = __expf(-0.5f * s[t][2]); st.w = __expf(-0.5f * s[t][3]);
            *(float4*)o = st;
        } else {
            float2 st;
            st.x = __expf(-0.5f * s[t][0]); st.y = __expf(-0.5f * s[t][1]);
            *(float2*)o = st;
        }
    }
}

// ---------------------------------------------------------------------------
// PAC transposed conv, stride 2, k=3, pad=1, out_pad=1.
// Template RX = x-parity of output pixels (compile-time tap set: RX=0 -> j=1
// only; RX=1 -> j={0,2}). blockIdx.z = y-parity. Each thread: 4 output pixels
// (x stride 2, same input row window) x OBLK output channels.
// Input-row tail beyond Wi is zeroed -> matches reference zero-padding.
// ---------------------------------------------------------------------------
template <int OBLK, int RX>
__global__ void pac_kernel(const float* __restrict__ xin, const float* __restrict__ kk,
                           const float* __restrict__ w, const float* __restrict__ bias,
                           float* __restrict__ out,
                           int C, int O, int Hi, int Wi, int Ho, int Wo) {
    constexpr int NJ = RX ? 2 : 1;
    extern __shared__ float wsm[];   // [C][9][OBLK]
    int o0 = blockIdx.y * OBLK;
    int n = C * 9 * OBLK;
    for (int t = threadIdx.x; t < n; t += blockDim.x) {
        int ob = t % OBLK;
        int tap = (t / OBLK) % 9;
        int c = t / (9 * OBLK);
        wsm[t] = w[((size_t)c * O + (o0 + ob)) * 9 + tap];
    }
    __syncthreads();
    int ry = blockIdx.z & 1;
    int Wh = Wo >> 1;
    int tpr = Wh >> 2;
    int idx = blockIdx.x * blockDim.x + threadIdx.x;
    int ys = idx / tpr;
    int xs0 = (idx % tpr) * 4;
    int y = 2 * ys + ry;
    int x0 = 2 * xs0 + RX;
    int HoWo = Ho * Wo, HiWi = Hi * Wi;
    size_t pix0 = (size_t)y * Wo + x0;

    float acc[OBLK][4];
#pragma unroll
    for (int ob = 0; ob < OBLK; ob++) {
        float b = bias[o0 + ob];
#pragma unroll
        for (int p = 0; p < 4; p++) acc[ob][p] = b;
    }

    // valid i taps: (y+i) odd && ym < Hi
    int ymv[2], itap[2], ni = 0;
#pragma unroll
    for (int i = 0; i < 3; i++) {
        int a = y + i;
        if (a & 1) {
            int ym = (a - 1) >> 1;
            if (ym < Hi) { ymv[ni] = ym; itap[ni] = i * 3; ni++; }
        }
    }
    bool tail = (xs0 + 4 < Wi);   // is r[4] in-bounds

    for (int ii = 0; ii < ni; ii++) {
        const float* xrow = xin + (size_t)ymv[ii] * Wi + xs0;
        float dot[NJ][OBLK][4];
#pragma unroll
        for (int jj = 0; jj < NJ; jj++)
#pragma unroll
            for (int ob = 0; ob < OBLK; ob++)
#pragma unroll
                for (int p = 0; p < 4; p++) dot[jj][ob][p] = 0.f;

        for (int c = 0; c < C; c++) {
            const float* xr = xrow + (size_t)c * HiWi;
            float r[5];
            float4 m = *(const float4*)xr;   // xs0 % 4 == 0 -> aligned
            r[0] = m.x; r[1] = m.y; r[2] = m.z; r[3] = m.w;
            r[4] = (NJ == 2 && tail) ? xr[4] : 0.f;
            const float* wc = wsm + (size_t)c * 9 * OBLK;
#pragma unroll
            for (int jj = 0; jj < NJ; jj++) {
                // RX=0: j=1, window offset 0.  RX=1: jj=0 -> j=0 off 0; jj=1 -> j=2 off 1.
                constexpr int joff[2] = {0, 1};
                int j = RX ? (jj * 2) : 1;
                const float* wt = wc + (itap[ii] + j) * OBLK;
#pragma unroll
                for (int ob = 0; ob < OBLK; ob++) {
                    float wv = wt[ob];
#pragma unroll
                    for (int p = 0; p < 4; p++)
                        dot[jj][ob][p] += r[joff[jj] + p] * wv;
                }
            }
        }
#pragma unroll
        for (int jj = 0; jj < NJ; jj++) {
            int j = RX ? (jj * 2) : 1;
            int tap = itap[ii] + j;
#pragma unroll
            for (int p = 0; p < 4; p++) {
                float kv = kk[(size_t)tap * HoWo + pix0 + 2 * p];
#pragma unroll
                for (int ob = 0; ob < OBLK; ob++)
                    acc[ob][p] += kv * dot[jj][ob][p];
            }
        }
    }
#pragma unroll
    for (int ob = 0; ob < OBLK; ob++)
#pragma unroll
        for (int p = 0; p < 4; p++)
            out[(size_t)(o0 + ob) * HoWo + pix0 + 2 * p] = acc[ob][p];
}

// ---------------------------------------------------------------------------
extern "C" void kernel_launch(void* const* d_in, const int* in_sizes, int n_in,
                              void* d_out, int out_size, void* d_ws, size_t ws_size,
                              hipStream_t stream) {
    const float* x      = (const float*)d_in[0];   // (256,64,64)
    const float* ef2    = (const float*)d_in[1];   // (128,128,128)
    const float* ef1    = (const float*)d_in[2];   // (64,256,256)
    const float* w_adj2 = (const float*)d_in[3];   // (256,128,3,3)
    const float* b_adj2 = (const float*)d_in[4];
    const float* w_adj1 = (const float*)d_in[5];   // (128,64,3,3)
    const float* b_adj1 = (const float*)d_in[6];
    const float* w_p16  = (const float*)d_in[7];   // (256,128,3,3)  (Cin,O,kh,kw)
    const float* b_p16  = (const float*)d_in[8];
    const float* w_p20  = (const float*)d_in[9];   // (128,64,3,3)
    const float* b_p20  = (const float*)d_in[10];
    const float* w_out  = (const float*)d_in[11];  // (3,64,3,3)
    const float* b_out  = (const float*)d_in[12];
    float* out = (float*)d_out;                    // (3,256,256)

    // Workspace layout (floats). Guides first; x-path reuses their regions.
    float* ws  = (float*)d_ws;
    float* bx0 = ws;                     // 1,048,576
    float* bk2 = ws + 1048576;           // 147,456
    float* bk1 = ws + 1196032;           // 589,824
    float* bg2 = ws + 1785856;           // 4,194,304 (dead after kk2)
    float* bg1 = ws + 5980160;           // 8,388,608 (dead after kk1)
    float* bx1 = bg2;                    // 2,097,152 aliases bg2
    float* bx2 = bg1;                    // 4,194,304 aliases bg1
    // peak = 14,368,768 floats = 57.5 MB

    // g2 = conv3x3(ef_lv2): 128 -> 256 @ 128x128
    conv3x3_kernel<4><<<dim3(16, 64), 256, 128 * 9 * 4 * sizeof(float), stream>>>(
        ef2, w_adj2, b_adj2, bg2, 128, 128, 128);
    // kk2 (guide = g2, 256 ch, 128x128): PIX=2, 64-thr blocks -> 128 blocks
    kk_kernel<2><<<dim3(128), 64, 0, stream>>>(bg2, bk2, 256, 128, 128);

    // g1 = conv3x3(ef_lv1): 64 -> 128 @ 256x256
    conv3x3_kernel<4><<<dim3(64, 32), 256, 64 * 9 * 4 * sizeof(float), stream>>>(
        ef1, w_adj1, b_adj1, bg1, 64, 256, 256);
    // kk1 (guide = g1, 128 ch, 256x256): PIX=4, 64-thr blocks -> 256 blocks
    kk_kernel<4><<<dim3(256), 64, 0, stream>>>(bg1, bk1, 128, 256, 256);

    // x-path: x = inorm(x)+x twice  (256, 64x64)
    inorm_res_kernel<<<256, 256, 0, stream>>>(x, bx0, 4096);
    inorm_res_kernel<<<256, 256, 0, stream>>>(bx0, bx0, 4096);

    // pac16: (256, 64x64) -> (128, 128x128)
    pac_kernel<4, 0><<<dim3(4, 32, 2), 256, 256 * 9 * 4 * sizeof(float), stream>>>(
        bx0, bk2, w_p16, b_p16, bx1, 256, 128, 64, 64, 128, 128);
    pac_kernel<4, 1><<<dim3(4, 32, 2), 256, 256 * 9 * 4 * sizeof(float), stream>>>(
        bx0, bk2, w_p16, b_p16, bx1, 256, 128, 64, 64, 128, 128);

    inorm_res_kernel<<<128, 256, 0, stream>>>(bx1, bx1, 16384);
    inorm_res_kernel<<<128, 256, 0, stream>>>(bx1, bx1, 16384);

    // pac20: (128, 128x128) -> (64, 256x256)
    pac_kernel<4, 0><<<dim3(16, 16, 2), 256, 128 * 9 * 4 * sizeof(float), stream>>>(
        bx1, bk1, w_p20, b_p20, bx2, 128, 64, 128, 128, 256, 256);
    pac_kernel<4, 1><<<dim3(16, 16, 2), 256, 128 * 9 * 4 * sizeof(float), stream>>>(
        bx1, bk1, w_p20, b_p20, bx2, 128, 64, 128, 128, 256, 256);

    inorm_res_kernel<<<64, 256, 0, stream>>>(bx2, bx2, 65536);
    inorm_res_kernel<<<64, 256, 0, stream>>>(bx2, bx2, 65536);

    // final conv: 64 -> 3 @ 256x256
    conv3x3_kernel<3><<<dim3(64, 1), 256, 64 * 9 * 3 * sizeof(float), stream>>>(
        bx2, w_out, b_out, out, 64, 256, 256);
}

// Round 4
// 767.757 us; speedup vs baseline: 1.9921x; 1.9921x over previous
//
#include <hip/hip_runtime.h>
#include <hip/hip_bf16.h>
#include <cstdint>
#include <cstddef>

#define EPS_IN 1e-5f

typedef __attribute__((ext_vector_type(8))) short short8;
typedef __attribute__((ext_vector_type(4))) float floatx4;
typedef __attribute__((ext_vector_type(8))) unsigned short ushort8;
typedef __attribute__((ext_vector_type(4))) unsigned int uint4v;
typedef __attribute__((address_space(3))) unsigned int lds_uint;
typedef __attribute__((address_space(1))) const unsigned int glb_uint;

__device__ __forceinline__ unsigned short f2bf(float f) {
    unsigned int u = __float_as_uint(f);
    u += 0x7FFFu + ((u >> 16) & 1u);     // RNE
    return (unsigned short)(u >> 16);
}

// ---------------------------------------------------------------------------
// zero fill (uint4 granularity)
// ---------------------------------------------------------------------------
__global__ void zero4_kernel(uint4v* __restrict__ p, long n4) {
    long i = (long)blockIdx.x * blockDim.x + threadIdx.x;
    long stride = (long)gridDim.x * blockDim.x;
    uint4v z = {0u, 0u, 0u, 0u};
    for (; i < n4; i += stride) p[i] = z;
}

// ---------------------------------------------------------------------------
// fp32 NCHW -> bf16 padded pixel-major [(H+2)][(W+2)][C]; interior only
// (borders pre-zeroed). thread t: p = t % HW (lane-consecutive), cg = t / HW.
// ---------------------------------------------------------------------------
__global__ void pad_convert_kernel(const float* __restrict__ in, unsigned short* __restrict__ xp,
                                   int C, int H, int W) {
    int HW = H * W;
    int t = blockIdx.x * blockDim.x + threadIdx.x;
    int p = t % HW;
    int cg = t / HW;
    int y = p / W, x = p % W;
    ushort8 v;
#pragma unroll
    for (int i = 0; i < 8; i++)
        v[i] = f2bf(in[(size_t)(cg * 8 + i) * HW + p]);
    *(ushort8*)&xp[((size_t)(y + 1) * (W + 2) + (x + 1)) * C + cg * 8] = v;
}

// ---------------------------------------------------------------------------
// w fp32 [O][C][9] -> W_re bf16 [9][O][C]
// ---------------------------------------------------------------------------
__global__ void reorder_w_kernel(const float* __restrict__ w, unsigned short* __restrict__ wre,
                                 int O, int C) {
    int cg8 = C >> 3;
    int t = blockIdx.x * blockDim.x + threadIdx.x;
    int cg = t % cg8;
    int o = (t / cg8) % O;
    int tap = t / (cg8 * O);
    if (tap >= 9) return;
    ushort8 v;
#pragma unroll
    for (int i = 0; i < 8; i++)
        v[i] = f2bf(w[((size_t)o * C + cg * 8 + i) * 9 + tap]);
    *(ushort8*)&wre[((size_t)tap * O + o) * C + cg * 8] = v;
}

// ---------------------------------------------------------------------------
// MFMA implicit-GEMM 3x3 SAME conv.
// out[O][H][W] fp32 = sum_{tap,c} W_re[tap][o][c] * X_p[y+dy][x+dx][c]
// Block: 256 thr = 4 waves (2x2), tile M=128 outch x N=128 px (row segment).
// Wave tile 64x64 via 16 x mfma_f32_16x16x32_bf16 per k-step.
// LDS: B = one 32-ch chunk of 3 rows x 130 cols (24.96 KB),
//      A = one 32-ch chunk of one dy (3 dx) x 128 o     (24.58 KB).
// Staged with global_load_lds width=16.
// ---------------------------------------------------------------------------
template <int CIN>
__launch_bounds__(256, 2)
__global__ void conv3x3_mfma_kernel(const unsigned short* __restrict__ xp,
                                    const unsigned short* __restrict__ wre,
                                    const float* __restrict__ bias,
                                    float* __restrict__ out,
                                    int O, int H, int W) {
    __shared__ short Bbuf[390 * 32];       // [dy*130+col][32 ch]
    __shared__ short Abuf[3 * 128 * 32];   // [dx*128+m][32 ch]
    int tid = threadIdx.x;
    int lane = tid & 63, wid = tid >> 6;
    int mi = wid >> 1, ni = wid & 1;
    int l15 = lane & 15, khi = lane >> 4;
    int tpr = W >> 7;                      // 128-px tiles per image row
    int y = blockIdx.x / tpr;
    int x0 = (blockIdx.x % tpr) << 7;
    int o0 = blockIdx.y << 7;
    int HW = H * W;
    int Wp = W + 2;

    floatx4 acc[4][4];
#pragma unroll
    for (int sm = 0; sm < 4; sm++)
#pragma unroll
        for (int r = 0; r < 4; r++) {
            float bv = bias[o0 + mi * 64 + sm * 16 + khi * 4 + r];
#pragma unroll
            for (int sn = 0; sn < 4; sn++) acc[sm][sn][r] = bv;
        }

    for (int cc = 0; cc < CIN / 32; cc++) {
        __syncthreads();                   // prior reads of Bbuf done
        // stage B chunk: 1560 x 16B slots
#pragma unroll
        for (int k = 0; k < 7; k++) {
            int s = k * 256 + tid;
            if (s < 1560) {
                int r = s >> 2, q = s & 3;
                int dy = r / 130, col = r % 130;
                const unsigned short* g =
                    xp + ((size_t)(y + dy) * Wp + x0 + col) * CIN + cc * 32 + q * 8;
                __builtin_amdgcn_global_load_lds((glb_uint*)g, (lds_uint*)(Bbuf + s * 8), 16, 0, 0);
            }
        }
        for (int dy = 0; dy < 3; dy++) {
            __syncthreads();               // prior reads of Abuf done (also drains B loads)
            // stage A chunk for this dy: 1536 x 16B slots (exact)
#pragma unroll
            for (int k = 0; k < 6; k++) {
                int s = k * 256 + tid;
                int dx = s >> 9, m = (s >> 2) & 127, q = s & 3;
                const unsigned short* g =
                    wre + ((size_t)((dy * 3 + dx) * O + o0 + m)) * CIN + cc * 32 + q * 8;
                __builtin_amdgcn_global_load_lds((glb_uint*)g, (lds_uint*)(Abuf + s * 8), 16, 0, 0);
            }
            __syncthreads();               // A (and B) visible
#pragma unroll
            for (int dx = 0; dx < 3; dx++) {
                short8 a[4], b[4];
#pragma unroll
                for (int sm = 0; sm < 4; sm++)
                    a[sm] = *(const short8*)&Abuf[(dx * 128 + mi * 64 + sm * 16 + l15) * 32 + khi * 8];
#pragma unroll
                for (int sn = 0; sn < 4; sn++)
                    b[sn] = *(const short8*)&Bbuf[(dy * 130 + ni * 64 + sn * 16 + l15 + dx) * 32 + khi * 8];
#pragma unroll
                for (int sm = 0; sm < 4; sm++)
#pragma unroll
                    for (int sn = 0; sn < 4; sn++)
                        acc[sm][sn] = __builtin_amdgcn_mfma_f32_16x16x32_bf16(
                            a[sm], b[sn], acc[sm][sn], 0, 0, 0);
            }
        }
    }
#pragma unroll
    for (int sm = 0; sm < 4; sm++)
#pragma unroll
        for (int sn = 0; sn < 4; sn++)
#pragma unroll
            for (int r = 0; r < 4; r++) {
                int o = o0 + mi * 64 + sm * 16 + khi * 4 + r;
                int px = x0 + ni * 64 + sn * 16 + l15;
                out[(size_t)o * HW + (size_t)y * W + px] = acc[sm][sn][r];
            }
}

// ---------------------------------------------------------------------------
// Instance-norm + residual (round-2 version)
// ---------------------------------------------------------------------------
__global__ void inorm_res_kernel(const float* __restrict__ in, float* __restrict__ out, int HW) {
    int c = blockIdx.x;
    const float* src = in + (size_t)c * HW;
    float* dst = out + (size_t)c * HW;
    float s = 0.f, q = 0.f;
    for (int i = threadIdx.x; i < HW; i += blockDim.x) {
        float v = src[i];
        s += v; q += v * v;
    }
#pragma unroll
    for (int off = 32; off >= 1; off >>= 1) {
        s += __shfl_down(s, off, 64);
        q += __shfl_down(q, off, 64);
    }
    __shared__ float ss[4], sq[4], mr[2];
    int wave = threadIdx.x >> 6;
    if ((threadIdx.x & 63) == 0) { ss[wave] = s; sq[wave] = q; }
    __syncthreads();
    if (threadIdx.x == 0) {
        float ts = ss[0] + ss[1] + ss[2] + ss[3];
        float tq = sq[0] + sq[1] + sq[2] + sq[3];
        float m = ts / (float)HW;
        float var = tq / (float)HW - m * m;
        mr[0] = m;
        mr[1] = rsqrtf(var + EPS_IN);
    }
    __syncthreads();
    float m = mr[0], r = mr[1];
    for (int i = threadIdx.x; i < HW; i += blockDim.x) {
        float v = src[i];
        dst[i] = (v - m) * r + v;
    }
}

// ---------------------------------------------------------------------------
// Plain direct 3x3 conv (round-2 version) — used only for the tiny final conv.
// ---------------------------------------------------------------------------
template <int OBLK>
__global__ void conv3x3_plain_kernel(const float* __restrict__ in, const float* __restrict__ w,
                                     const float* __restrict__ bias, float* __restrict__ out,
                                     int Cin, int H, int W) {
    extern __shared__ float wsm[];   // [Cin][9][OBLK]
    int o0 = blockIdx.y * OBLK;
    int n = Cin * 9 * OBLK;
    for (int t = threadIdx.x; t < n; t += blockDim.x) {
        int ob = t % OBLK;
        int tap = (t / OBLK) % 9;
        int c = t / (9 * OBLK);
        wsm[t] = w[((size_t)(o0 + ob) * Cin + c) * 9 + tap];
    }
    __syncthreads();
    int HW = H * W;
    int pix = blockIdx.x * blockDim.x + threadIdx.x;
    if (pix >= HW) return;
    int y = pix / W, x = pix % W;
    float acc[OBLK];
#pragma unroll
    for (int ob = 0; ob < OBLK; ob++) acc[ob] = bias[o0 + ob];
    bool xl = (x > 0), xr = (x < W - 1);
    for (int c = 0; c < Cin; c++) {
        const float* base = in + (size_t)c * HW + pix;
        const float* wc = wsm + (size_t)c * 9 * OBLK;
#pragma unroll
        for (int dy = 0; dy < 3; dy++) {
            int yy = y + dy - 1;
            if (yy < 0 || yy >= H) continue;
            const float* row = base + (dy - 1) * W;
            float v0 = xl ? row[-1] : 0.f;
            float v1 = row[0];
            float v2 = xr ? row[1] : 0.f;
#pragma unroll
            for (int ob = 0; ob < OBLK; ob++) {
                acc[ob] += v0 * wc[(dy * 3 + 0) * OBLK + ob];
                acc[ob] += v1 * wc[(dy * 3 + 1) * OBLK + ob];
                acc[ob] += v2 * wc[(dy * 3 + 2) * OBLK + ob];
            }
        }
    }
#pragma unroll
    for (int ob = 0; ob < OBLK; ob++)
        out[(size_t)(o0 + ob) * HW + pix] = acc[ob];
}

// ---------------------------------------------------------------------------
// PAC kk (round-2 version): kk[tap][y][x] = exp(-0.5*sum_c (gp-g)^2)
// ---------------------------------------------------------------------------
__global__ void kk_kernel(const float* __restrict__ g, float* __restrict__ kkout,
                          int Cg, int H, int W) {
    int tap = blockIdx.y;
    int i = tap / 3, j = tap % 3;
    int HW = H * W;
    int pix = blockIdx.x * blockDim.x + threadIdx.x;
    if (pix >= HW) return;
    int y = pix / W, x = pix % W;
    int gy = y + i - 1, gx = x + j - 1;
    bool inb = (gy >= 0 && gy < H && gx >= 0 && gx < W);
    const float* pn = g + (inb ? ((size_t)gy * W + gx) : 0);
    float s = 0.f;
    for (int c = 0; c < Cg; c++) {
        float a = inb ? pn[(size_t)c * HW] : 0.f;
        float d = a - g[(size_t)c * HW + pix];
        s += d * d;
    }
    kkout[(size_t)tap * HW + pix] = __expf(-0.5f * s);
}

// ---------------------------------------------------------------------------
// PAC transposed conv (round-2 version), stride2 k3 pad1 outpad1.
// ---------------------------------------------------------------------------
template <int OBLK>
__global__ void pac_kernel(const float* __restrict__ xin, const float* __restrict__ kk,
                           const float* __restrict__ w, const float* __restrict__ bias,
                           float* __restrict__ out,
                           int C, int O, int Hi, int Wi, int Ho, int Wo) {
    extern __shared__ float wsm[];   // [C][9][OBLK]
    int o0 = blockIdx.y * OBLK;
    int n = C * 9 * OBLK;
    for (int t = threadIdx.x; t < n; t += blockDim.x) {
        int ob = t % OBLK;
        int tap = (t / OBLK) % 9;
        int c = t / (9 * OBLK);
        wsm[t] = w[((size_t)c * O + (o0 + ob)) * 9 + tap];
    }
    __syncthreads();
    int ry = (blockIdx.z >> 1) & 1, rx = blockIdx.z & 1;
    int Wh = Wo >> 1;
    int p = blockIdx.x * blockDim.x + threadIdx.x;
    int ys = p / Wh, xs = p % Wh;
    int y = 2 * ys + ry, x = 2 * xs + rx;
    int HoWo = Ho * Wo, HiWi = Hi * Wi;
    int pix = y * Wo + x;
    float acc[OBLK];
#pragma unroll
    for (int ob = 0; ob < OBLK; ob++) acc[ob] = bias[o0 + ob];
#pragma unroll
    for (int i = 0; i < 3; i++) {
        int a = y + i;
        if (!(a & 1)) continue;
        int ym = (a - 1) >> 1;
        if (ym >= Hi) continue;
#pragma unroll
        for (int j = 0; j < 3; j++) {
            int bcol = x + j;
            if (!(bcol & 1)) continue;
            int xm = (bcol - 1) >> 1;
            if (xm >= Wi) continue;
            int tap = i * 3 + j;
            float kv = kk[(size_t)tap * HoWo + pix];
            const float* xb = xin + (size_t)ym * Wi + xm;
            const float* wb = wsm + tap * OBLK;
            float dot[OBLK];
#pragma unroll
            for (int ob = 0; ob < OBLK; ob++) dot[ob] = 0.f;
            for (int c = 0; c < C; c++) {
                float xv = xb[(size_t)c * HiWi];
#pragma unroll
                for (int ob = 0; ob < OBLK; ob++) dot[ob] += xv * wb[(size_t)c * 9 * OBLK + ob];
            }
#pragma unroll
            for (int ob = 0; ob < OBLK; ob++) acc[ob] += kv * dot[ob];
        }
    }
#pragma unroll
    for (int ob = 0; ob < OBLK; ob++)
        out[(size_t)(o0 + ob) * HoWo + pix] = acc[ob];
}

// ---------------------------------------------------------------------------
extern "C" void kernel_launch(void* const* d_in, const int* in_sizes, int n_in,
                              void* d_out, int out_size, void* d_ws, size_t ws_size,
                              hipStream_t stream) {
    const float* x      = (const float*)d_in[0];   // (256,64,64)
    const float* ef2    = (const float*)d_in[1];   // (128,128,128)
    const float* ef1    = (const float*)d_in[2];   // (64,256,256)
    const float* w_adj2 = (const float*)d_in[3];   // (256,128,3,3)
    const float* b_adj2 = (const float*)d_in[4];
    const float* w_adj1 = (const float*)d_in[5];   // (128,64,3,3)
    const float* b_adj1 = (const float*)d_in[6];
    const float* w_p16  = (const float*)d_in[7];   // (256,128,3,3)
    const float* b_p16  = (const float*)d_in[8];
    const float* w_p20  = (const float*)d_in[9];   // (128,64,3,3)
    const float* b_p20  = (const float*)d_in[10];
    const float* w_out  = (const float*)d_in[11];  // (3,64,3,3)
    const float* b_out  = (const float*)d_in[12];
    float* out = (float*)d_out;                    // (3,256,256)

    // Workspace layout (float units). fp32 intermediates first, then bf16
    // staging areas. peak ~71.1 MB.
    float* ws  = (float*)d_ws;
    float* bx0 = ws;                               // 1,048,576 f
    float* bk2 = ws + 1048576;                     //   147,456 f
    float* bk1 = ws + 1196032;                     //   589,824 f
    float* bg2 = ws + 1785856;                     // 4,194,304 f (later bx1)
    float* bg1 = ws + 5980160;                     // 8,388,608 f (later bx2)
    unsigned short* Xp2 = (unsigned short*)(ws + 14368768);  // 130*130*128 bf16 = 1,081,600 f
    unsigned short* Xp1 = (unsigned short*)(ws + 15450368);  // 258*258*64 bf16  = 2,130,048 f
    unsigned short* Wr2 = (unsigned short*)(ws + 17580416);  // 9*256*128 bf16   =   147,456 f
    unsigned short* Wr1 = (unsigned short*)(ws + 17727872);  // 9*128*64 bf16    =    36,864 f
    float* bx1 = bg2;
    float* bx2 = bg1;

    // zero padded bf16 input buffers (borders must be 0; ws is poisoned 0xAA)
    zero4_kernel<<<1024, 256, 0, stream>>>((uint4v*)Xp2, 130L * 130 * 128 * 2 / 16);
    zero4_kernel<<<1024, 256, 0, stream>>>((uint4v*)Xp1, 258L * 258 * 64 * 2 / 16);

    // ---- guide 2: g2 = conv3x3(ef_lv2), 128 -> 256 @ 128x128 ----
    pad_convert_kernel<<<1024, 256, 0, stream>>>(ef2, Xp2, 128, 128, 128);
    reorder_w_kernel<<<144, 256, 0, stream>>>(w_adj2, Wr2, 256, 128);
    conv3x3_mfma_kernel<128><<<dim3(128, 2), 256, 0, stream>>>(
        Xp2, Wr2, b_adj2, bg2, 256, 128, 128);
    kk_kernel<<<dim3(64, 9), 256, 0, stream>>>(bg2, bk2, 256, 128, 128);

    // ---- guide 1: g1 = conv3x3(ef_lv1), 64 -> 128 @ 256x256 ----
    pad_convert_kernel<<<2048, 256, 0, stream>>>(ef1, Xp1, 64, 256, 256);
    reorder_w_kernel<<<36, 256, 0, stream>>>(w_adj1, Wr1, 128, 64);
    conv3x3_mfma_kernel<64><<<dim3(512, 1), 256, 0, stream>>>(
        Xp1, Wr1, b_adj1, bg1, 128, 256, 256);
    kk_kernel<<<dim3(256, 9), 256, 0, stream>>>(bg1, bk1, 128, 256, 256);

    // ---- x-path ----
    inorm_res_kernel<<<256, 256, 0, stream>>>(x, bx0, 4096);
    inorm_res_kernel<<<256, 256, 0, stream>>>(bx0, bx0, 4096);

    // pac16: (256, 64x64) -> (128, 128x128)
    pac_kernel<4><<<dim3(16, 32, 4), 256, 256 * 9 * 4 * sizeof(float), stream>>>(
        bx0, bk2, w_p16, b_p16, bx1, 256, 128, 64, 64, 128, 128);

    inorm_res_kernel<<<128, 256, 0, stream>>>(bx1, bx1, 16384);
    inorm_res_kernel<<<128, 256, 0, stream>>>(bx1, bx1, 16384);

    // pac20: (128, 128x128) -> (64, 256x256)
    pac_kernel<4><<<dim3(64, 16, 4), 256, 128 * 9 * 4 * sizeof(float), stream>>>(
        bx1, bk1, w_p20, b_p20, bx2, 128, 64, 128, 128, 256, 256);

    inorm_res_kernel<<<64, 256, 0, stream>>>(bx2, bx2, 65536);
    inorm_res_kernel<<<64, 256, 0, stream>>>(bx2, bx2, 65536);

    // final conv: 64 -> 3 @ 256x256
    conv3x3_plain_kernel<1><<<dim3(256, 3), 256, 64 * 9 * 1 * sizeof(float), stream>>>(
        bx2, w_out, b_out, out, 64, 256, 256);
}

// Round 5
// 375.478 us; speedup vs baseline: 4.0733x; 2.0447x over previous
//
#include <hip/hip_runtime.h>
#include <hip/hip_bf16.h>
#include <cstdint>
#include <cstddef>

#define EPS_IN 1e-5f

typedef __attribute__((ext_vector_type(8))) short short8;
typedef __attribute__((ext_vector_type(4))) float floatx4;
typedef __attribute__((ext_vector_type(8))) unsigned short ushort8;
typedef __attribute__((ext_vector_type(4))) unsigned short ushort4v;
typedef __attribute__((ext_vector_type(4))) unsigned int uint4v;
typedef __attribute__((address_space(3))) unsigned int lds_uint;
typedef __attribute__((address_space(1))) const unsigned int glb_uint;

__device__ __forceinline__ unsigned short f2bf(float f) {
    unsigned int u = __float_as_uint(f);
    u += 0x7FFFu + ((u >> 16) & 1u);     // RNE
    return (unsigned short)(u >> 16);
}
__device__ __forceinline__ float bf2f(unsigned short s) {
    return __uint_as_float((unsigned int)s << 16);
}

// ---------------------------------------------------------------------------
__global__ void zero4_kernel(uint4v* __restrict__ p, long n4) {
    long i = (long)blockIdx.x * blockDim.x + threadIdx.x;
    long stride = (long)gridDim.x * blockDim.x;
    uint4v z = {0u, 0u, 0u, 0u};
    for (; i < n4; i += stride) p[i] = z;
}

// ---------------------------------------------------------------------------
// fp32 NCHW -> bf16 padded pixel-major [(H+2)][(W+2)][C]; interior only.
// ---------------------------------------------------------------------------
__global__ void pad_convert_kernel(const float* __restrict__ in, unsigned short* __restrict__ xp,
                                   int C, int H, int W) {
    int HW = H * W;
    int t = blockIdx.x * blockDim.x + threadIdx.x;
    int p = t % HW;
    int cg = t / HW;
    int y = p / W, x = p % W;
    ushort8 v;
#pragma unroll
    for (int i = 0; i < 8; i++)
        v[i] = f2bf(in[(size_t)(cg * 8 + i) * HW + p]);
    *(ushort8*)&xp[((size_t)(y + 1) * (W + 2) + (x + 1)) * C + cg * 8] = v;
}

// ---------------------------------------------------------------------------
// w fp32 [O][C][9] -> W_re bf16 [9][O][C]   (for the guide convs)
// ---------------------------------------------------------------------------
__global__ void reorder_w_kernel(const float* __restrict__ w, unsigned short* __restrict__ wre,
                                 int O, int C) {
    int cg8 = C >> 3;
    int t = blockIdx.x * blockDim.x + threadIdx.x;
    int cg = t % cg8;
    int o = (t / cg8) % O;
    int tap = t / (cg8 * O);
    if (tap >= 9) return;
    ushort8 v;
#pragma unroll
    for (int i = 0; i < 8; i++)
        v[i] = f2bf(w[((size_t)o * C + cg * 8 + i) * 9 + tap]);
    *(ushort8*)&wre[((size_t)tap * O + o) * C + cg * 8] = v;
}

// ---------------------------------------------------------------------------
// MFMA implicit-GEMM 3x3 SAME conv; output = bf16 pixel-major PADDED guide
// gp[(H+2)][(W+2)][O] (borders pre-zeroed).
// ---------------------------------------------------------------------------
template <int CIN>
__launch_bounds__(256, 2)
__global__ void conv3x3_mfma_kernel(const unsigned short* __restrict__ xp,
                                    const unsigned short* __restrict__ wre,
                                    const float* __restrict__ bias,
                                    unsigned short* __restrict__ gp,
                                    int O, int H, int W) {
    __shared__ short Bbuf[390 * 32];       // [dy*130+col][32 ch]
    __shared__ short Abuf[3 * 128 * 32];   // [dx*128+m][32 ch]
    int tid = threadIdx.x;
    int lane = tid & 63, wid = tid >> 6;
    int mi = wid >> 1, ni = wid & 1;
    int l15 = lane & 15, khi = lane >> 4;
    int tpr = W >> 7;
    int y = blockIdx.x / tpr;
    int x0 = (blockIdx.x % tpr) << 7;
    int o0 = blockIdx.y << 7;
    int Wp = W + 2;

    floatx4 acc[4][4];
#pragma unroll
    for (int sm = 0; sm < 4; sm++)
#pragma unroll
        for (int r = 0; r < 4; r++) {
            float bv = bias[o0 + mi * 64 + sm * 16 + khi * 4 + r];
#pragma unroll
            for (int sn = 0; sn < 4; sn++) acc[sm][sn][r] = bv;
        }

    for (int cc = 0; cc < CIN / 32; cc++) {
        __syncthreads();
#pragma unroll
        for (int k = 0; k < 7; k++) {
            int s = k * 256 + tid;
            if (s < 1560) {
                int r = s >> 2, q = s & 3;
                int dy = r / 130, col = r % 130;
                const unsigned short* g =
                    xp + ((size_t)(y + dy) * Wp + x0 + col) * CIN + cc * 32 + q * 8;
                __builtin_amdgcn_global_load_lds((glb_uint*)g, (lds_uint*)(Bbuf + s * 8), 16, 0, 0);
            }
        }
        for (int dy = 0; dy < 3; dy++) {
            __syncthreads();
#pragma unroll
            for (int k = 0; k < 6; k++) {
                int s = k * 256 + tid;
                int dx = s >> 9, m = (s >> 2) & 127, q = s & 3;
                const unsigned short* g =
                    wre + ((size_t)((dy * 3 + dx) * O + o0 + m)) * CIN + cc * 32 + q * 8;
                __builtin_amdgcn_global_load_lds((glb_uint*)g, (lds_uint*)(Abuf + s * 8), 16, 0, 0);
            }
            __syncthreads();
#pragma unroll
            for (int dx = 0; dx < 3; dx++) {
                short8 a[4], b[4];
#pragma unroll
                for (int sm = 0; sm < 4; sm++)
                    a[sm] = *(const short8*)&Abuf[(dx * 128 + mi * 64 + sm * 16 + l15) * 32 + khi * 8];
#pragma unroll
                for (int sn = 0; sn < 4; sn++)
                    b[sn] = *(const short8*)&Bbuf[(dy * 130 + ni * 64 + sn * 16 + l15 + dx) * 32 + khi * 8];
#pragma unroll
                for (int sm = 0; sm < 4; sm++)
#pragma unroll
                    for (int sn = 0; sn < 4; sn++)
                        acc[sm][sn] = __builtin_amdgcn_mfma_f32_16x16x32_bf16(
                            a[sm], b[sn], acc[sm][sn], 0, 0, 0);
            }
        }
    }
#pragma unroll
    for (int sm = 0; sm < 4; sm++)
#pragma unroll
        for (int sn = 0; sn < 4; sn++) {
            int ob = o0 + mi * 64 + sm * 16 + khi * 4;
            int px = x0 + ni * 64 + sn * 16 + l15;
            ushort4v st;
#pragma unroll
            for (int r = 0; r < 4; r++) st[r] = f2bf(acc[sm][sn][r]);
            *(ushort4v*)&gp[((size_t)(y + 1) * Wp + (px + 1)) * O + ob] = st;
        }
}

// ---------------------------------------------------------------------------
// kk partial sums from bf16 pixel-major padded guide. Channel-chunk parallel:
// S[t][pix] += sum_{c in chunk} (g[nbr]-g[ctr])^2 via atomicAdd (S pre-zeroed).
// ---------------------------------------------------------------------------
__global__ void kk_partial_kernel(const unsigned short* __restrict__ gp, float* __restrict__ S,
                                  int C, int H, int W, int CC) {
    int p = blockIdx.x * blockDim.x + threadIdx.x;
    int y = p / W, x = p % W;
    int Wp = W + 2;
    int c0 = blockIdx.y * CC;
    int HW = H * W;
    float s[9];
#pragma unroll
    for (int t = 0; t < 9; t++) s[t] = 0.f;
    const unsigned short* ctr = gp + ((size_t)(y + 1) * Wp + (x + 1)) * C + c0;
    for (int cg = 0; cg < CC; cg += 8) {
        ushort8 cv = *(const ushort8*)(ctr + cg);
        float cf[8];
#pragma unroll
        for (int i = 0; i < 8; i++) cf[i] = bf2f(cv[i]);
#pragma unroll
        for (int t = 0; t < 9; t++) {
            int dy = t / 3, dx = t % 3;
            ushort8 nv = *(const ushort8*)(gp + ((size_t)(y + dy) * Wp + (x + dx)) * C + c0 + cg);
#pragma unroll
            for (int i = 0; i < 8; i++) {
                float d = bf2f(nv[i]) - cf[i];
                s[t] += d * d;
            }
        }
    }
#pragma unroll
    for (int t = 0; t < 9; t++)
        atomicAdd(&S[(size_t)t * HW + p], s[t]);
}

__global__ void exp_kernel(float* __restrict__ S, int n) {
    int i = blockIdx.x * blockDim.x + threadIdx.x;
    if (i < n) S[i] = __expf(-0.5f * S[i]);
}

// ---------------------------------------------------------------------------
// Instance-norm split: stats (per 4096-elem chunk partials) + apply.
// ---------------------------------------------------------------------------
__global__ void in_stats_kernel(const float* __restrict__ in, float2* __restrict__ part,
                                int HW, int NB) {
    int c = blockIdx.y, bi = blockIdx.x;
    const float* src = in + (size_t)c * HW + (size_t)bi * 4096;
    float s = 0.f, q = 0.f;
#pragma unroll
    for (int k = 0; k < 4; k++) {
        float4 v = *(const float4*)(src + k * 1024 + threadIdx.x * 4);
        s += v.x + v.y + v.z + v.w;
        q += v.x * v.x + v.y * v.y + v.z * v.z + v.w * v.w;
    }
#pragma unroll
    for (int off = 32; off >= 1; off >>= 1) {
        s += __shfl_down(s, off, 64);
        q += __shfl_down(q, off, 64);
    }
    __shared__ float ss[4], sq[4];
    int wave = threadIdx.x >> 6;
    if ((threadIdx.x & 63) == 0) { ss[wave] = s; sq[wave] = q; }
    __syncthreads();
    if (threadIdx.x == 0) {
        float2 o;
        o.x = ss[0] + ss[1] + ss[2] + ss[3];
        o.y = sq[0] + sq[1] + sq[2] + sq[3];
        part[c * NB + bi] = o;
    }
}

__global__ void in_apply_kernel(const float* __restrict__ in, float* __restrict__ out,
                                const float2* __restrict__ part, int HW, int NB) {
    int c = blockIdx.y, bi = blockIdx.x;
    float s = 0.f, q = 0.f;
    for (int nb = 0; nb < NB; nb++) {
        float2 pp = part[c * NB + nb];
        s += pp.x; q += pp.y;
    }
    float m = s / (float)HW;
    float r = rsqrtf(q / (float)HW - m * m + EPS_IN);
    const float* src = in + (size_t)c * HW + (size_t)bi * 4096;
    float* dst = out + (size_t)c * HW + (size_t)bi * 4096;
#pragma unroll
    for (int k = 0; k < 4; k++) {
        float4 v = *(const float4*)(src + k * 1024 + threadIdx.x * 4);
        float4 o;
        o.x = (v.x - m) * r + v.x;
        o.y = (v.y - m) * r + v.y;
        o.z = (v.z - m) * r + v.z;
        o.w = (v.w - m) * r + v.w;
        *(float4*)(dst + k * 1024 + threadIdx.x * 4) = o;
    }
}

// ---------------------------------------------------------------------------
// fp32 NCHW -> bf16 pixel-major [HW][C] (no padding)
// ---------------------------------------------------------------------------
__global__ void transpose_x_kernel(const float* __restrict__ in, unsigned short* __restrict__ xt,
                                   int C, int HW) {
    int t = blockIdx.x * blockDim.x + threadIdx.x;
    int p = t % HW;
    int cg = t / HW;
    ushort8 v;
#pragma unroll
    for (int i = 0; i < 8; i++)
        v[i] = f2bf(in[(size_t)(cg * 8 + i) * HW + p]);
    *(ushort8*)&xt[(size_t)p * C + cg * 8] = v;
}

// ---------------------------------------------------------------------------
// PAC weights fp32 [C][O][3][3] -> stacked bf16 [t*O+o][C]
// ---------------------------------------------------------------------------
__global__ void stack_w_kernel(const float* __restrict__ w, unsigned short* __restrict__ wst,
                               int C, int O) {
    int cg8 = C >> 3;
    int t = blockIdx.x * blockDim.x + threadIdx.x;
    int cg = t % cg8;
    int o = (t / cg8) % O;
    int tap = t / (cg8 * O);
    if (tap >= 9) return;
    ushort8 v;
#pragma unroll
    for (int i = 0; i < 8; i++)
        v[i] = f2bf(w[((size_t)(cg * 8 + i) * O + o) * 9 + tap]);
    *(ushort8*)&wst[((size_t)tap * O + o) * C + cg * 8] = v;
}

// ---------------------------------------------------------------------------
// GEMM: P[M][N] bf16 = A[M][K] bf16 x B[N][K] bf16 (K-contig both).
// Block 128x128, 4 waves 2x2, wave 64x64, K-chunks of 32.
// ---------------------------------------------------------------------------
template <int K>
__launch_bounds__(256, 2)
__global__ void gemm_bt_kernel(const unsigned short* __restrict__ A,
                               const unsigned short* __restrict__ B,
                               unsigned short* __restrict__ P, int N) {
    __shared__ short Ab[128 * 32];
    __shared__ short Bb[128 * 32];
    int tid = threadIdx.x;
    int lane = tid & 63, wid = tid >> 6;
    int mi = wid >> 1, ni = wid & 1;
    int l15 = lane & 15, khi = lane >> 4;
    int m0 = blockIdx.y << 7, n0 = blockIdx.x << 7;

    floatx4 acc[4][4];
#pragma unroll
    for (int sm = 0; sm < 4; sm++)
#pragma unroll
        for (int sn = 0; sn < 4; sn++)
#pragma unroll
            for (int r = 0; r < 4; r++) acc[sm][sn][r] = 0.f;

    for (int kc = 0; kc < K / 32; kc++) {
        __syncthreads();
#pragma unroll
        for (int k = 0; k < 2; k++) {
            int s = k * 256 + tid;
            int row = s >> 2, q = s & 3;
            const unsigned short* ga = A + (size_t)(m0 + row) * K + kc * 32 + q * 8;
            __builtin_amdgcn_global_load_lds((glb_uint*)ga, (lds_uint*)(Ab + s * 8), 16, 0, 0);
            const unsigned short* gb = B + (size_t)(n0 + row) * K + kc * 32 + q * 8;
            __builtin_amdgcn_global_load_lds((glb_uint*)gb, (lds_uint*)(Bb + s * 8), 16, 0, 0);
        }
        __syncthreads();
        short8 a[4], b[4];
#pragma unroll
        for (int sm = 0; sm < 4; sm++)
            a[sm] = *(const short8*)&Ab[(mi * 64 + sm * 16 + l15) * 32 + khi * 8];
#pragma unroll
        for (int sn = 0; sn < 4; sn++)
            b[sn] = *(const short8*)&Bb[(ni * 64 + sn * 16 + l15) * 32 + khi * 8];
#pragma unroll
        for (int sm = 0; sm < 4; sm++)
#pragma unroll
            for (int sn = 0; sn < 4; sn++)
                acc[sm][sn] = __builtin_amdgcn_mfma_f32_16x16x32_bf16(
                    a[sm], b[sn], acc[sm][sn], 0, 0, 0);
    }
#pragma unroll
    for (int sm = 0; sm < 4; sm++)
#pragma unroll
        for (int sn = 0; sn < 4; sn++) {
            int m = m0 + mi * 64 + sm * 16 + khi * 4;
            int n = n0 + ni * 64 + sn * 16 + l15;
#pragma unroll
            for (int r = 0; r < 4; r++)
                P[(size_t)(m + r) * N + n] = f2bf(acc[sm][sn][r]);
        }
}

// ---------------------------------------------------------------------------
// PAC combine: out[o][y][x] = b[o] + sum_valid_taps kk[t][y][x] *
//   P[t*O+o][ym][xm],  ym=(y+i-1)/2 (valid iff (y+i) odd && ym<Hi), same x.
// Thread: 4 consecutive o at one output pixel.
// ---------------------------------------------------------------------------
__global__ void pac_combine_kernel(const unsigned short* __restrict__ P,
                                   const float* __restrict__ kk,
                                   const float* __restrict__ bias,
                                   float* __restrict__ out,
                                   int O, int Hi, int Wi, int Ho, int Wo) {
    int HoWo = Ho * Wo, HiWi = Hi * Wi;
    int idx = blockIdx.x * blockDim.x + threadIdx.x;
    int pix = idx % HoWo;
    int og = idx / HoWo;
    int y = pix / Wo, x = pix % Wo;
    float acc[4];
#pragma unroll
    for (int r = 0; r < 4; r++) acc[r] = bias[og * 4 + r];
#pragma unroll
    for (int t = 0; t < 9; t++) {
        int i = t / 3, j = t % 3;
        int a = y + i;
        if (!(a & 1)) continue;
        int ym = (a - 1) >> 1;
        if (ym >= Hi) continue;
        int bcol = x + j;
        if (!(bcol & 1)) continue;
        int xm = (bcol - 1) >> 1;
        if (xm >= Wi) continue;
        float kv = kk[(size_t)t * HoWo + pix];
        const unsigned short* pb = P + (size_t)(t * O + og * 4) * HiWi + (size_t)ym * Wi + xm;
#pragma unroll
        for (int r = 0; r < 4; r++)
            acc[r] += kv * bf2f(pb[(size_t)r * HiWi]);
    }
#pragma unroll
    for (int r = 0; r < 4; r++)
        out[(size_t)(og * 4 + r) * HoWo + pix] = acc[r];
}

// ---------------------------------------------------------------------------
// Plain direct 3x3 conv — final 64->3 conv only.
// ---------------------------------------------------------------------------
template <int OBLK>
__global__ void conv3x3_plain_kernel(const float* __restrict__ in, const float* __restrict__ w,
                                     const float* __restrict__ bias, float* __restrict__ out,
                                     int Cin, int H, int W) {
    extern __shared__ float wsm[];
    int o0 = blockIdx.y * OBLK;
    int n = Cin * 9 * OBLK;
    for (int t = threadIdx.x; t < n; t += blockDim.x) {
        int ob = t % OBLK;
        int tap = (t / OBLK) % 9;
        int c = t / (9 * OBLK);
        wsm[t] = w[((size_t)(o0 + ob) * Cin + c) * 9 + tap];
    }
    __syncthreads();
    int HW = H * W;
    int pix = blockIdx.x * blockDim.x + threadIdx.x;
    if (pix >= HW) return;
    int y = pix / W, x = pix % W;
    float acc[OBLK];
#pragma unroll
    for (int ob = 0; ob < OBLK; ob++) acc[ob] = bias[o0 + ob];
    bool xl = (x > 0), xr = (x < W - 1);
    for (int c = 0; c < Cin; c++) {
        const float* base = in + (size_t)c * HW + pix;
        const float* wc = wsm + (size_t)c * 9 * OBLK;
#pragma unroll
        for (int dy = 0; dy < 3; dy++) {
            int yy = y + dy - 1;
            if (yy < 0 || yy >= H) continue;
            const float* row = base + (dy - 1) * W;
            float v0 = xl ? row[-1] : 0.f;
            float v1 = row[0];
            float v2 = xr ? row[1] : 0.f;
#pragma unroll
            for (int ob = 0; ob < OBLK; ob++) {
                acc[ob] += v0 * wc[(dy * 3 + 0) * OBLK + ob];
                acc[ob] += v1 * wc[(dy * 3 + 1) * OBLK + ob];
                acc[ob] += v2 * wc[(dy * 3 + 2) * OBLK + ob];
            }
        }
    }
#pragma unroll
    for (int ob = 0; ob < OBLK; ob++)
        out[(size_t)(o0 + ob) * HW + pix] = acc[ob];
}

// ---------------------------------------------------------------------------
extern "C" void kernel_launch(void* const* d_in, const int* in_sizes, int n_in,
                              void* d_out, int out_size, void* d_ws, size_t ws_size,
                              hipStream_t stream) {
    const float* x      = (const float*)d_in[0];   // (256,64,64)
    const float* ef2    = (const float*)d_in[1];   // (128,128,128)
    const float* ef1    = (const float*)d_in[2];   // (64,256,256)
    const float* w_adj2 = (const float*)d_in[3];   // (256,128,3,3)
    const float* b_adj2 = (const float*)d_in[4];
    const float* w_adj1 = (const float*)d_in[5];   // (128,64,3,3)
    const float* b_adj1 = (const float*)d_in[6];
    const float* w_p16  = (const float*)d_in[7];   // (256,128,3,3)
    const float* b_p16  = (const float*)d_in[8];
    const float* w_p20  = (const float*)d_in[9];   // (128,64,3,3)
    const float* b_p20  = (const float*)d_in[10];
    const float* w_out  = (const float*)d_in[11];  // (3,64,3,3)
    const float* b_out  = (const float*)d_in[12];
    float* out = (float*)d_out;                    // (3,256,256)

    // ---- workspace layout (float offsets), peak 75.7 MB ----
    float* ws = (float*)d_ws;
    float* bx0 = ws;                          // 1,048,576
    float* bx1 = ws + 1048576;                // 2,097,152
    float* bx2 = ws + 3145728;                // 4,194,304
    float* bk2 = ws + 7340032;                //   147,456 (9*16384)
    float* bk1 = ws + 7487488;                //   589,824 (9*65536)
    float2* stat = (float2*)(ws + 8077312);   //     8,192
    // region B (5,242,880 f): Gp1 -> {P16, Xt16, Wt16} -> P20
    unsigned short* Gp1  = (unsigned short*)(ws + 8085504);   // 258*258*128 bf16
    unsigned short* P16  = (unsigned short*)(ws + 8085504);   // 1152*4096 bf16
    unsigned short* Xt16 = (unsigned short*)(ws + 10444800);  // 4096*256 bf16
    unsigned short* Wt16 = (unsigned short*)(ws + 10969088);  // 1152*256 bf16
    unsigned short* P20  = (unsigned short*)(ws + 8085504);   // 640*16384 bf16
    // region C (2,163,200 f): Gp2 -> Xt20
    unsigned short* Gp2  = (unsigned short*)(ws + 13328384);  // 130*130*256 bf16
    unsigned short* Xt20 = (unsigned short*)(ws + 13328384);  // 16384*128 bf16
    // region D (3,395,968 f): Xp2 | Wr2 | Xp1 | Wr1 (no aliasing)
    unsigned short* Xp2 = (unsigned short*)(ws + 15491584);   // 130*130*128
    unsigned short* Wr2 = (unsigned short*)(ws + 16573184);   // 9*256*128
    unsigned short* Xp1 = (unsigned short*)(ws + 16720640);   // 258*258*64
    unsigned short* Wr1 = (unsigned short*)(ws + 18850688);   // 9*128*64
    // region E: Wt20 (padded to 640 rows; pad rows stay zero)
    unsigned short* Wt20 = (unsigned short*)(ws + 18887552);  // 640*128
    // end: 18,928,512 floats

    // one zero pass over everything that needs zero init (bk/S, pads, borders)
    zero4_kernel<<<1024, 256, 0, stream>>>((uint4v*)(ws + 7340032), (18928512L - 7340032L) / 4);

    // ---- guide 2: 128 -> 256 @ 128x128, pixel-major bf16 padded ----
    pad_convert_kernel<<<1024, 256, 0, stream>>>(ef2, Xp2, 128, 128, 128);
    reorder_w_kernel<<<144, 256, 0, stream>>>(w_adj2, Wr2, 256, 128);
    conv3x3_mfma_kernel<128><<<dim3(128, 2), 256, 0, stream>>>(Xp2, Wr2, b_adj2, Gp2, 256, 128, 128);
    kk_partial_kernel<<<dim3(64, 4), 256, 0, stream>>>(Gp2, bk2, 256, 128, 128, 64);

    // ---- guide 1: 64 -> 128 @ 256x256 ----
    pad_convert_kernel<<<2048, 256, 0, stream>>>(ef1, Xp1, 64, 256, 256);
    reorder_w_kernel<<<36, 256, 0, stream>>>(w_adj1, Wr1, 128, 64);
    conv3x3_mfma_kernel<64><<<dim3(512, 1), 256, 0, stream>>>(Xp1, Wr1, b_adj1, Gp1, 128, 256, 256);
    kk_partial_kernel<<<dim3(256, 2), 256, 0, stream>>>(Gp1, bk1, 128, 256, 256, 64);

    // exp over bk2|bk1 (contiguous 737,280 floats)
    exp_kernel<<<2880, 256, 0, stream>>>(bk2, 737280);

    // ---- x-path: inorm x2 on (256, 64x64) ----
    in_stats_kernel<<<dim3(1, 256), 256, 0, stream>>>(x, stat, 4096, 1);
    in_apply_kernel<<<dim3(1, 256), 256, 0, stream>>>(x, bx0, stat, 4096, 1);
    in_stats_kernel<<<dim3(1, 256), 256, 0, stream>>>(bx0, stat, 4096, 1);
    in_apply_kernel<<<dim3(1, 256), 256, 0, stream>>>(bx0, bx0, stat, 4096, 1);

    // pac16: GEMM (M=1152, N=4096, K=256) + combine -> bx1 (128, 128x128)
    transpose_x_kernel<<<512, 256, 0, stream>>>(bx0, Xt16, 256, 4096);
    stack_w_kernel<<<144, 256, 0, stream>>>(w_p16, Wt16, 256, 128);
    gemm_bt_kernel<256><<<dim3(32, 9), 256, 0, stream>>>(Wt16, Xt16, P16, 4096);
    pac_combine_kernel<<<2048, 256, 0, stream>>>(P16, bk2, b_p16, bx1, 128, 64, 64, 128, 128);

    in_stats_kernel<<<dim3(4, 128), 256, 0, stream>>>(bx1, stat, 16384, 4);
    in_apply_kernel<<<dim3(4, 128), 256, 0, stream>>>(bx1, bx1, stat, 16384, 4);
    in_stats_kernel<<<dim3(4, 128), 256, 0, stream>>>(bx1, stat, 16384, 4);
    in_apply_kernel<<<dim3(4, 128), 256, 0, stream>>>(bx1, bx1, stat, 16384, 4);

    // pac20: GEMM (M=640 pad, N=16384, K=128) + combine -> bx2 (64, 256x256)
    transpose_x_kernel<<<1024, 256, 0, stream>>>(bx1, Xt20, 128, 16384);
    stack_w_kernel<<<36, 256, 0, stream>>>(w_p20, Wt20, 128, 64);
    gemm_bt_kernel<128><<<dim3(128, 5), 256, 0, stream>>>(Wt20, Xt20, P20, 16384);
    pac_combine_kernel<<<4096, 256, 0, stream>>>(P20, bk1, b_p20, bx2, 64, 128, 128, 256, 256);

    in_stats_kernel<<<dim3(16, 64), 256, 0, stream>>>(bx2, stat, 65536, 16);
    in_apply_kernel<<<dim3(16, 64), 256, 0, stream>>>(bx2, bx2, stat, 65536, 16);
    in_stats_kernel<<<dim3(16, 64), 256, 0, stream>>>(bx2, stat, 65536, 16);
    in_apply_kernel<<<dim3(16, 64), 256, 0, stream>>>(bx2, bx2, stat, 65536, 16);

    // final conv: 64 -> 3 @ 256x256
    conv3x3_plain_kernel<1><<<dim3(256, 3), 256, 64 * 9 * 1 * sizeof(float), stream>>>(
        bx2, w_out, b_out, out, 64, 256, 256);
}